// Round 1
// baseline (222.085 us; speedup 1.0000x reference)
//
#include <hip/hip_runtime.h>

#define E 1024
#define NSEQ 2048
#define HEADS 16
#define HD 64
#define ATT_SCALE 0.125f

typedef unsigned short u16;
typedef short short8 __attribute__((ext_vector_type(8)));
typedef float f32x4 __attribute__((ext_vector_type(4)));

__device__ __forceinline__ u16 f2bf(float f) {
    union { float f; unsigned u; } v; v.f = f;
    unsigned r = v.u + 0x7fffu + ((v.u >> 16) & 1u);
    return (u16)(r >> 16);
}

__device__ __forceinline__ f32x4 mfma16(short8 a, short8 b, f32x4 c) {
    return __builtin_amdgcn_mfma_f32_16x16x32_bf16(a, b, c, 0, 0, 0);
}

// ---------------- weight f32 -> bf16 convert ----------------
__global__ __launch_bounds__(256) void convw_k(
    const float* __restrict__ Wq, const float* __restrict__ Wk,
    const float* __restrict__ Wv, const float* __restrict__ Wo,
    u16* __restrict__ out)
{
    const unsigned i = (blockIdx.x * 256u + threadIdx.x) * 4u;  // 4M elems total
    const unsigned m = i >> 20;
    const float* src = (m == 0) ? Wq : (m == 1) ? Wk : (m == 2) ? Wv : Wo;
    const float4 v = *(const float4*)(src + (i & 0xFFFFFu));
    *(uint2*)(out + i) = make_uint2(
        ((unsigned)f2bf(v.x)) | (((unsigned)f2bf(v.y)) << 16),
        ((unsigned)f2bf(v.z)) | (((unsigned)f2bf(v.w)) << 16));
}

// ---------------- LayerNorm (f32 in, bf16 out) ----------------
__global__ __launch_bounds__(256) void ln_fwd(
    const float* __restrict__ X, const float* __restrict__ w,
    const float* __restrict__ bb, u16* __restrict__ xn)
{
    const int row = blockIdx.x, tid = threadIdx.x;
    const int lane = tid & 63, wave = tid >> 6;
    const float4 v = ((const float4*)(X + (size_t)row * E))[tid];
    float s = v.x + v.y + v.z + v.w;
    float s2 = v.x * v.x + v.y * v.y + v.z * v.z + v.w * v.w;
#pragma unroll
    for (int off = 1; off < 64; off <<= 1) {
        s += __shfl_xor(s, off);
        s2 += __shfl_xor(s2, off);
    }
    __shared__ float red[8];
    if (lane == 0) { red[wave] = s; red[4 + wave] = s2; }
    __syncthreads();
    s = red[0] + red[1] + red[2] + red[3];
    s2 = red[4] + red[5] + red[6] + red[7];
    const float mu = s * (1.f / 1024.f);
    float var = s2 * (1.f / 1024.f) - mu * mu;
    var = fmaxf(var, 0.f);
    const float rs = rsqrtf(var + 1e-5f);
    const float4 wv = ((const float4*)w)[tid];
    const float4 bv = ((const float4*)bb)[tid];
    u16 o0 = f2bf((v.x - mu) * rs * wv.x + bv.x);
    u16 o1 = f2bf((v.y - mu) * rs * wv.y + bv.y);
    u16 o2 = f2bf((v.z - mu) * rs * wv.z + bv.z);
    u16 o3 = f2bf((v.w - mu) * rs * wv.w + bv.w);
    *(uint2*)(xn + (size_t)row * E + tid * 4) =
        make_uint2(((unsigned)o0) | (((unsigned)o1) << 16),
                   ((unsigned)o2) | (((unsigned)o3) << 16));
}

// ---------------- NT GEMM: C[M,1024] = A[M,1024] * B[1024,1024]^T ----------------
// MODE 0: bf16 out at outb + z*4096*1024 (weights at Wbase + z*2^20)
// MODE 1: f32 out = acc + resid + bias
template<int MODE>
__global__ __launch_bounds__(256) void gemm_nt(
    const u16* __restrict__ A, const u16* __restrict__ Wbase,
    u16* __restrict__ outb, float* __restrict__ outf,
    const float* __restrict__ resid, const float* __restrict__ bias)
{
    __shared__ __align__(16) unsigned char As[128 * 128];  // 128 rows x 64 bf16
    __shared__ __align__(16) unsigned char Bs[128 * 128];
    const int tid = threadIdx.x;
    const int lane = tid & 63, wave = tid >> 6;
    const int l15 = lane & 15, l4 = lane >> 4;
    const int wm = wave >> 1, wn = wave & 1;
    const int nt = blockIdx.x, mt = blockIdx.y, z = blockIdx.z;
    const u16* Bw = Wbase + (size_t)z * (E * (size_t)E);

    const int r0 = tid >> 3, slot = tid & 7;

    f32x4 acc[4][4] = {};

    for (int kt = 0; kt < 16; ++kt) {
        short8 va[4], vb[4];
#pragma unroll
        for (int it = 0; it < 4; ++it) {
            int row = it * 32 + r0;
            va[it] = *(const short8*)(A + (size_t)(mt * 128 + row) * E + kt * 64 + slot * 8);
            vb[it] = *(const short8*)(Bw + (size_t)(nt * 128 + row) * E + kt * 64 + slot * 8);
        }
#pragma unroll
        for (int it = 0; it < 4; ++it) {
            int row = it * 32 + r0;
            int off = (row * 128 + slot * 16) ^ ((row & 7) << 4);
            *(short8*)(As + off) = va[it];
            *(short8*)(Bs + off) = vb[it];
        }
        __syncthreads();
#pragma unroll
        for (int ks = 0; ks < 2; ++ks) {
            short8 af[4], bfr[4];
#pragma unroll
            for (int i = 0; i < 4; ++i) {
                int ra = wm * 64 + i * 16 + l15;
                af[i] = *(const short8*)(As + ((ra * 128 + ks * 64 + l4 * 16) ^ ((ra & 7) << 4)));
                int rb = wn * 64 + i * 16 + l15;
                bfr[i] = *(const short8*)(Bs + ((rb * 128 + ks * 64 + l4 * 16) ^ ((rb & 7) << 4)));
            }
#pragma unroll
            for (int i = 0; i < 4; ++i)
#pragma unroll
                for (int j = 0; j < 4; ++j)
                    acc[i][j] = mfma16(af[i], bfr[j], acc[i][j]);
        }
        __syncthreads();
    }

    const int orow0 = mt * 128 + wm * 64, ocol0 = nt * 128 + wn * 64;
    if (MODE == 0) {
        u16* outz = outb + (size_t)z * (4096 * (size_t)E);
#pragma unroll
        for (int i = 0; i < 4; ++i)
#pragma unroll
            for (int j = 0; j < 4; ++j)
#pragma unroll
                for (int r = 0; r < 4; ++r) {
                    int row = orow0 + i * 16 + l4 * 4 + r;
                    int col = ocol0 + j * 16 + l15;
                    outz[(size_t)row * E + col] = f2bf(acc[i][j][r]);
                }
    } else {
#pragma unroll
        for (int i = 0; i < 4; ++i)
#pragma unroll
            for (int j = 0; j < 4; ++j)
#pragma unroll
                for (int r = 0; r < 4; ++r) {
                    int row = orow0 + i * 16 + l4 * 4 + r;
                    int col = ocol0 + j * 16 + l15;
                    size_t idx = (size_t)row * E + col;
                    outf[idx] = acc[i][j][r] + resid[idx] + bias[col];
                }
    }
}

// ---------------- causal flash attention ----------------
// grid (N/64, H, B), block 256 (4 waves x 16 q-rows). KVBLK=64, D=64.
__global__ __launch_bounds__(256) void attn_fwd(
    const u16* __restrict__ Q, const u16* __restrict__ K,
    const u16* __restrict__ V, u16* __restrict__ O)
{
    __shared__ __align__(16) unsigned char Ks[64 * 128];      // K tile [kv][d]
    __shared__ __align__(16) unsigned char Vt[64 * 128];      // V^T tile [d][kv]
    __shared__ __align__(16) unsigned char Ps[4 * 16 * 128];  // per-wave P strip [16][64]
    const int tid = threadIdx.x, lane = tid & 63, wave = tid >> 6;
    const int l15 = lane & 15, l4 = lane >> 4;
    const int qb = blockIdx.x, h = blockIdx.y, b = blockIdx.z;
    const int q0 = qb * 64;
    const size_t bbase = (size_t)b * NSEQ * E + h * HD;

    // Q strip into registers: lane holds q=(l15), d = ks*32 + l4*8 .. +8
    const int qrow = q0 + wave * 16 + l15;
    short8 aq[2];
#pragma unroll
    for (int ks = 0; ks < 2; ++ks)
        aq[ks] = *(const short8*)(Q + bbase + (size_t)qrow * E + ks * 32 + l4 * 8);

    f32x4 accO[4] = {};
    float mrow[4], lrow[4];
#pragma unroll
    for (int r = 0; r < 4; ++r) { mrow[r] = -1e30f; lrow[r] = 0.f; }

    const int r0 = tid >> 3, slot = tid & 7;  // K staging mapping
    const int vkv = lane, vd0 = wave * 16;    // V staging mapping

    for (int kt = 0; kt <= qb; ++kt) {
        const u16* Kg = K + bbase + (size_t)(kt * 64) * E;
        const u16* Vg = V + bbase + (size_t)(kt * 64) * E;
        short8 kstage[2], vstage[2];
#pragma unroll
        for (int it = 0; it < 2; ++it) {
            int row = it * 32 + r0;
            kstage[it] = *(const short8*)(Kg + (size_t)row * E + slot * 8);
        }
#pragma unroll
        for (int u = 0; u < 2; ++u)
            vstage[u] = *(const short8*)(Vg + (size_t)vkv * E + vd0 + u * 8);
#pragma unroll
        for (int it = 0; it < 2; ++it) {
            int row = it * 32 + r0;
            *(short8*)(Ks + ((row * 128 + slot * 16) ^ ((row & 7) << 4))) = kstage[it];
        }
#pragma unroll
        for (int u = 0; u < 2; ++u)
#pragma unroll
            for (int j = 0; j < 8; ++j) {
                int d = vd0 + u * 8 + j;
                *(u16*)(Vt + (d * 128 + ((vkv * 2) ^ ((d & 7) << 4)))) = (u16)vstage[u][j];
            }
        __syncthreads();

        // S = Q K^T  (4 col-tiles of 16 kv)
        f32x4 s[4];
#pragma unroll
        for (int kc = 0; kc < 4; ++kc) {
            f32x4 z = {0.f, 0.f, 0.f, 0.f};
#pragma unroll
            for (int ks = 0; ks < 2; ++ks) {
                int kr = kc * 16 + l15;
                short8 kf = *(const short8*)(Ks + ((kr * 128 + ks * 64 + l4 * 16) ^ ((kr & 7) << 4)));
                z = mfma16(aq[ks], kf, z);
            }
            s[kc] = z;
        }

        // scale + causal mask + running max
        float pmax[4] = {-1e30f, -1e30f, -1e30f, -1e30f};
#pragma unroll
        for (int kc = 0; kc < 4; ++kc) {
            int kvg = kt * 64 + kc * 16 + l15;
#pragma unroll
            for (int r = 0; r < 4; ++r) {
                int qg = q0 + wave * 16 + l4 * 4 + r;
                float v = s[kc][r] * ATT_SCALE;
                if (kvg > qg) v = -1e30f;
                s[kc][r] = v;
                pmax[r] = fmaxf(pmax[r], v);
            }
        }
#pragma unroll
        for (int r = 0; r < 4; ++r) {
            pmax[r] = fmaxf(pmax[r], __shfl_xor(pmax[r], 1));
            pmax[r] = fmaxf(pmax[r], __shfl_xor(pmax[r], 2));
            pmax[r] = fmaxf(pmax[r], __shfl_xor(pmax[r], 4));
            pmax[r] = fmaxf(pmax[r], __shfl_xor(pmax[r], 8));
        }
        float psum[4] = {0.f, 0.f, 0.f, 0.f};
#pragma unroll
        for (int r = 0; r < 4; ++r) {
            float mn = fmaxf(mrow[r], pmax[r]);
            float sc = __expf(mrow[r] - mn);
            mrow[r] = mn;
            lrow[r] *= sc;
#pragma unroll
            for (int dt = 0; dt < 4; ++dt) accO[dt][r] *= sc;
        }
#pragma unroll
        for (int kc = 0; kc < 4; ++kc)
#pragma unroll
            for (int r = 0; r < 4; ++r) {
                float p = __expf(s[kc][r] - mrow[r]);
                psum[r] += p;
                s[kc][r] = p;
            }
#pragma unroll
        for (int r = 0; r < 4; ++r) {
            psum[r] += __shfl_xor(psum[r], 1);
            psum[r] += __shfl_xor(psum[r], 2);
            psum[r] += __shfl_xor(psum[r], 4);
            psum[r] += __shfl_xor(psum[r], 8);
            lrow[r] += psum[r];
        }

        // P (f32, C-layout) -> bf16 -> per-wave LDS strip (transpose for A-operand)
        unsigned char* Pw = Ps + wave * 2048;
#pragma unroll
        for (int kc = 0; kc < 4; ++kc)
#pragma unroll
            for (int r = 0; r < 4; ++r) {
                int pr = l4 * 4 + r, pc = kc * 16 + l15;
                *(u16*)(Pw + (pr * 128 + ((pc * 2) ^ ((pr & 7) << 4)))) = f2bf(s[kc][r]);
            }

        // O += P @ V
#pragma unroll
        for (int ks2 = 0; ks2 < 2; ++ks2) {
            short8 pf = *(const short8*)(Pw + ((l15 * 128 + ks2 * 64 + l4 * 16) ^ ((l15 & 7) << 4)));
#pragma unroll
            for (int dt = 0; dt < 4; ++dt) {
                int d = dt * 16 + l15;
                short8 vf = *(const short8*)(Vt + ((d * 128 + ks2 * 64 + l4 * 16) ^ ((d & 7) << 4)));
                accO[dt] = mfma16(pf, vf, accO[dt]);
            }
        }
        __syncthreads();
    }

    // epilogue: O = acc / l
#pragma unroll
    for (int dt = 0; dt < 4; ++dt)
#pragma unroll
        for (int r = 0; r < 4; ++r) {
            int qg = q0 + wave * 16 + l4 * 4 + r;
            int d = dt * 16 + l15;
            O[bbase + (size_t)qg * E + d] = f2bf(accO[dt][r] / lrow[r]);
        }
}

extern "C" void kernel_launch(void* const* d_in, const int* in_sizes, int n_in,
                              void* d_out, int out_size, void* d_ws, size_t ws_size,
                              hipStream_t stream)
{
    const float* x    = (const float*)d_in[0];
    const float* ln_w = (const float*)d_in[1];
    const float* ln_b = (const float*)d_in[2];
    const float* Wq   = (const float*)d_in[3];
    const float* Wk   = (const float*)d_in[4];
    const float* Wv   = (const float*)d_in[5];
    const float* Wo   = (const float*)d_in[6];
    const float* bo   = (const float*)d_in[7];
    float* out = (float*)d_out;

    u16* ws  = (u16*)d_ws;
    u16* Wbf = ws;                                  // 4 * 2^20 bf16
    u16* xn  = Wbf + (size_t)4 * 1024 * 1024;       // 4096*1024
    u16* Qb  = xn + (size_t)4096 * 1024;
    u16* Kb  = Qb + (size_t)4096 * 1024;
    u16* Vb  = Kb + (size_t)4096 * 1024;
    u16* Ob  = Vb + (size_t)4096 * 1024;

    convw_k<<<dim3(4096), dim3(256), 0, stream>>>(Wq, Wk, Wv, Wo, Wbf);
    ln_fwd<<<dim3(4096), dim3(256), 0, stream>>>(x, ln_w, ln_b, xn);
    gemm_nt<0><<<dim3(8, 32, 3), dim3(256), 0, stream>>>(
        xn, Wbf, Qb, nullptr, nullptr, nullptr);
    attn_fwd<<<dim3(32, 16, 2), dim3(256), 0, stream>>>(Qb, Kb, Vb, Ob);
    gemm_nt<1><<<dim3(8, 32, 1), dim3(256), 0, stream>>>(
        Ob, Wbf + (size_t)3 * 1024 * 1024, nullptr, out, x, bo);
}

// Round 2
// 167.663 us; speedup vs baseline: 1.3246x; 1.3246x over previous
//
#include <hip/hip_runtime.h>

#define E 1024
#define NSEQ 2048
#define HEADS 16
#define HD 64

typedef unsigned short u16;
typedef short short8 __attribute__((ext_vector_type(8)));
typedef float f32x4 __attribute__((ext_vector_type(4)));
typedef u16 u16x4 __attribute__((ext_vector_type(4)));

template<bool B> struct BC { static constexpr bool v = B; };

__device__ __forceinline__ u16 f2bf(float f) {
    union { float f; unsigned u; } v; v.f = f;
    unsigned r = v.u + 0x7fffu + ((v.u >> 16) & 1u);
    return (u16)(r >> 16);
}

__device__ __forceinline__ f32x4 mfma16(short8 a, short8 b, f32x4 c) {
    return __builtin_amdgcn_mfma_f32_16x16x32_bf16(a, b, c, 0, 0, 0);
}

// ---------------- weight f32 -> bf16 convert ----------------
__global__ __launch_bounds__(256) void convw_k(
    const float* __restrict__ Wq, const float* __restrict__ Wk,
    const float* __restrict__ Wv, const float* __restrict__ Wo,
    u16* __restrict__ out)
{
    const unsigned i = (blockIdx.x * 256u + threadIdx.x) * 4u;
    const unsigned m = i >> 20;
    const float* src = (m == 0) ? Wq : (m == 1) ? Wk : (m == 2) ? Wv : Wo;
    const float4 v = *(const float4*)(src + (i & 0xFFFFFu));
    *(uint2*)(out + i) = make_uint2(
        ((unsigned)f2bf(v.x)) | (((unsigned)f2bf(v.y)) << 16),
        ((unsigned)f2bf(v.z)) | (((unsigned)f2bf(v.w)) << 16));
}

// ---------------- LayerNorm (f32 in, bf16 out) ----------------
__global__ __launch_bounds__(256) void ln_fwd(
    const float* __restrict__ X, const float* __restrict__ w,
    const float* __restrict__ bb, u16* __restrict__ xn)
{
    const int row = blockIdx.x, tid = threadIdx.x;
    const int lane = tid & 63, wave = tid >> 6;
    const float4 v = ((const float4*)(X + (size_t)row * E))[tid];
    float s = v.x + v.y + v.z + v.w;
    float s2 = v.x * v.x + v.y * v.y + v.z * v.z + v.w * v.w;
#pragma unroll
    for (int off = 1; off < 64; off <<= 1) {
        s += __shfl_xor(s, off);
        s2 += __shfl_xor(s2, off);
    }
    __shared__ float red[8];
    if (lane == 0) { red[wave] = s; red[4 + wave] = s2; }
    __syncthreads();
    s = red[0] + red[1] + red[2] + red[3];
    s2 = red[4] + red[5] + red[6] + red[7];
    const float mu = s * (1.f / 1024.f);
    float var = s2 * (1.f / 1024.f) - mu * mu;
    var = fmaxf(var, 0.f);
    const float rs = rsqrtf(var + 1e-5f);
    const float4 wv = ((const float4*)w)[tid];
    const float4 bv = ((const float4*)bb)[tid];
    u16 o0 = f2bf((v.x - mu) * rs * wv.x + bv.x);
    u16 o1 = f2bf((v.y - mu) * rs * wv.y + bv.y);
    u16 o2 = f2bf((v.z - mu) * rs * wv.z + bv.z);
    u16 o3 = f2bf((v.w - mu) * rs * wv.w + bv.w);
    *(uint2*)(xn + (size_t)row * E + tid * 4) =
        make_uint2(((unsigned)o0) | (((unsigned)o1) << 16),
                   ((unsigned)o2) | (((unsigned)o3) << 16));
}

// ---------------- NT GEMM: C[M,1024] = A[M,1024] * B[1024,1024]^T ----------------
// MODE 0: bf16 out at outb + z*4096*1024 (weights at Wbase + z*2^20); z==0 scaled by 0.125
// MODE 1: f32 out = acc + resid + bias
template<int MODE>
__global__ __launch_bounds__(256) void gemm_nt(
    const u16* __restrict__ A, const u16* __restrict__ Wbase,
    u16* __restrict__ outb, float* __restrict__ outf,
    const float* __restrict__ resid, const float* __restrict__ bias)
{
    __shared__ __align__(16) unsigned char As[128 * 128];
    __shared__ __align__(16) unsigned char Bs[128 * 128];
    const int tid = threadIdx.x;
    const int lane = tid & 63, wave = tid >> 6;
    const int l15 = lane & 15, l4 = lane >> 4;
    const int wm = wave >> 1, wn = wave & 1;
    const int nt = blockIdx.x, mt = blockIdx.y, z = blockIdx.z;
    const u16* Bw = Wbase + (size_t)z * (E * (size_t)E);

    const int r0 = tid >> 3, slot = tid & 7;

    f32x4 acc[4][4] = {};

    for (int kt = 0; kt < 16; ++kt) {
        short8 va[4], vb[4];
#pragma unroll
        for (int it = 0; it < 4; ++it) {
            int row = it * 32 + r0;
            va[it] = *(const short8*)(A + (size_t)(mt * 128 + row) * E + kt * 64 + slot * 8);
            vb[it] = *(const short8*)(Bw + (size_t)(nt * 128 + row) * E + kt * 64 + slot * 8);
        }
#pragma unroll
        for (int it = 0; it < 4; ++it) {
            int row = it * 32 + r0;
            int off = (row * 128 + slot * 16) ^ ((row & 7) << 4);
            *(short8*)(As + off) = va[it];
            *(short8*)(Bs + off) = vb[it];
        }
        __syncthreads();
#pragma unroll
        for (int ks = 0; ks < 2; ++ks) {
            short8 af[4], bfr[4];
#pragma unroll
            for (int i = 0; i < 4; ++i) {
                int ra = wm * 64 + i * 16 + l15;
                af[i] = *(const short8*)(As + ((ra * 128 + ks * 64 + l4 * 16) ^ ((ra & 7) << 4)));
                int rb = wn * 64 + i * 16 + l15;
                bfr[i] = *(const short8*)(Bs + ((rb * 128 + ks * 64 + l4 * 16) ^ ((rb & 7) << 4)));
            }
#pragma unroll
            for (int i = 0; i < 4; ++i)
#pragma unroll
                for (int j = 0; j < 4; ++j)
                    acc[i][j] = mfma16(af[i], bfr[j], acc[i][j]);
        }
        __syncthreads();
    }

    const int orow0 = mt * 128 + wm * 64, ocol0 = nt * 128 + wn * 64;
    if (MODE == 0) {
        u16* outz = outb + (size_t)z * (4096 * (size_t)E);
        const float osc = (z == 0) ? 0.125f : 1.0f;
#pragma unroll
        for (int i = 0; i < 4; ++i)
#pragma unroll
            for (int j = 0; j < 4; ++j)
#pragma unroll
                for (int r = 0; r < 4; ++r) {
                    int row = orow0 + i * 16 + l4 * 4 + r;
                    int col = ocol0 + j * 16 + l15;
                    outz[(size_t)row * E + col] = f2bf(acc[i][j][r] * osc);
                }
    } else {
#pragma unroll
        for (int i = 0; i < 4; ++i)
#pragma unroll
            for (int j = 0; j < 4; ++j)
#pragma unroll
                for (int r = 0; r < 4; ++r) {
                    int row = orow0 + i * 16 + l4 * 4 + r;
                    int col = ocol0 + j * 16 + l15;
                    size_t idx = (size_t)row * E + col;
                    outf[idx] = acc[i][j][r] + resid[idx] + bias[col];
                }
    }
}

// ---------------- causal flash attention v2 ----------------
// grid (N/128, H, B), block 256 (4 waves x 32 q-rows). KVBLK=64, D=64.
// Swapped QK^T (lane owns one q-column), dbuf K/V, 1 barrier/K-tile.
// Q is pre-scaled by 0.125 in the QKV GEMM.
__global__ __launch_bounds__(256) void attn_fwd(
    const u16* __restrict__ Q, const u16* __restrict__ K,
    const u16* __restrict__ V, u16* __restrict__ O)
{
    __shared__ __align__(16) unsigned char Ks[2 * 64 * 128];   // K dbuf [kv][d]
    __shared__ __align__(16) unsigned char Vt[2 * 64 * 128];   // V^T dbuf [d][kv]
    __shared__ __align__(16) unsigned char Ps[4 * 32 * 128];   // per-wave P [32 q][64 kv]
    const int tid = threadIdx.x, lane = tid & 63, wave = tid >> 6;
    const int l15 = lane & 15, l4 = lane >> 4;
    const int qb = blockIdx.x, h = blockIdx.y, b = blockIdx.z;
    const int qw0 = qb * 128 + wave * 32;
    const size_t bbase = (size_t)b * NSEQ * E + h * HD;

    // Q frags (B-operand rows): lane holds Q[qw0+qt*16+l15][ks*32+l4*8 ..+8]
    short8 aq[2][2];
#pragma unroll
    for (int qt = 0; qt < 2; ++qt)
#pragma unroll
        for (int ks = 0; ks < 2; ++ks)
            aq[qt][ks] = *(const short8*)(Q + bbase + (size_t)(qw0 + qt * 16 + l15) * E + ks * 32 + l4 * 8);

    f32x4 accO[2][4] = {};
    float mrow[2] = {-1e30f, -1e30f};
    float lrow[2] = {0.f, 0.f};

    const int r0 = tid >> 3, slot = tid & 7;
    unsigned char* Pw = Ps + wave * 4096;
    const int last = 2 * qb + 1;

    // prologue: stage tile 0 -> buffer 0
    {
        const u16* Kg = K + bbase;
        const u16* Vg = V + bbase;
        short8 kst[2], vst[2];
#pragma unroll
        for (int it = 0; it < 2; ++it)
            kst[it] = *(const short8*)(Kg + (size_t)(it * 32 + r0) * E + slot * 8);
#pragma unroll
        for (int u = 0; u < 2; ++u)
            vst[u] = *(const short8*)(Vg + (size_t)lane * E + wave * 16 + u * 8);
#pragma unroll
        for (int it = 0; it < 2; ++it) {
            int row = it * 32 + r0;
            *(short8*)(Ks + row * 128 + ((slot * 16) ^ ((row & 7) << 4))) = kst[it];
        }
#pragma unroll
        for (int u = 0; u < 2; ++u)
#pragma unroll
            for (int j = 0; j < 8; ++j) {
                int d = wave * 16 + u * 8 + j;
                *(u16*)(Vt + d * 128 + ((lane * 2) ^ ((d & 7) << 4))) = (u16)vst[u][j];
            }
    }
    __syncthreads();
    int c = 0;

    auto step = [&](int kt, auto mc) {
        constexpr bool MASK = decltype(mc)::v;
        const bool pre = kt < last;
        // prefetch next tile into regs
        short8 kst[2], vst[2];
        if (pre) {
            const u16* Kg = K + bbase + (size_t)((kt + 1) * 64) * E;
            const u16* Vg = V + bbase + (size_t)((kt + 1) * 64) * E;
#pragma unroll
            for (int it = 0; it < 2; ++it)
                kst[it] = *(const short8*)(Kg + (size_t)(it * 32 + r0) * E + slot * 8);
#pragma unroll
            for (int u = 0; u < 2; ++u)
                vst[u] = *(const short8*)(Vg + (size_t)lane * E + wave * 16 + u * 8);
        }
        const unsigned char* Kc = Ks + c * 8192;
        const unsigned char* Vc = Vt + c * 8192;

        // S^T = K_tile . Q^T : lane owns q = qw0+qt*16+l15, kv = kt*64+kvt*16+l4*4+r
        f32x4 s[2][4] = {};
#pragma unroll
        for (int kvt = 0; kvt < 4; ++kvt) {
            const int kr = kvt * 16 + l15;
#pragma unroll
            for (int ks = 0; ks < 2; ++ks) {
                short8 kf = *(const short8*)(Kc + kr * 128 + ((ks * 64 + l4 * 16) ^ ((kr & 7) << 4)));
                s[0][kvt] = mfma16(kf, aq[0][ks], s[0][kvt]);
                s[1][kvt] = mfma16(kf, aq[1][ks], s[1][kvt]);
            }
        }
        if constexpr (MASK) {
#pragma unroll
            for (int qt = 0; qt < 2; ++qt) {
                const int qg = qw0 + qt * 16 + l15;
#pragma unroll
                for (int kvt = 0; kvt < 4; ++kvt)
#pragma unroll
                    for (int r = 0; r < 4; ++r) {
                        int kvg = kt * 64 + kvt * 16 + l4 * 4 + r;
                        if (kvg > qg) s[qt][kvt][r] = -1e30f;
                    }
            }
        }
        // online softmax (per-lane q column)
        float mn[2], sc[2];
#pragma unroll
        for (int qt = 0; qt < 2; ++qt) {
            float pm = s[qt][0][0];
#pragma unroll
            for (int kvt = 0; kvt < 4; ++kvt)
#pragma unroll
                for (int r = 0; r < 4; ++r)
                    pm = fmaxf(pm, s[qt][kvt][r]);
            pm = fmaxf(pm, __shfl_xor(pm, 16));
            pm = fmaxf(pm, __shfl_xor(pm, 32));
            mn[qt] = fmaxf(mrow[qt], pm);
            sc[qt] = __expf(mrow[qt] - mn[qt]);
            mrow[qt] = mn[qt];
        }
        // rescale accO (needs sc of accO's q = rt*16 + l4*4 + r)
#pragma unroll
        for (int rt = 0; rt < 2; ++rt)
#pragma unroll
            for (int r = 0; r < 4; ++r) {
                float scv = __shfl(sc[rt], l4 * 4 + r);
#pragma unroll
                for (int dt = 0; dt < 4; ++dt) accO[rt][dt][r] *= scv;
            }
        // exp, pack P -> LDS (b64), row sums
        float psum[2] = {0.f, 0.f};
#pragma unroll
        for (int qt = 0; qt < 2; ++qt) {
            const int pr = qt * 16 + l15;
#pragma unroll
            for (int kvt = 0; kvt < 4; ++kvt) {
                u16x4 pk;
#pragma unroll
                for (int r = 0; r < 4; ++r) {
                    float pv = __expf(s[qt][kvt][r] - mn[qt]);
                    psum[qt] += pv;
                    pk[r] = f2bf(pv);
                }
                *(u16x4*)(Pw + pr * 128 + ((kvt * 32 + l4 * 8) ^ ((pr & 7) << 4))) = pk;
            }
        }
#pragma unroll
        for (int qt = 0; qt < 2; ++qt) {
            float ps = psum[qt];
            ps += __shfl_xor(ps, 16);
            ps += __shfl_xor(ps, 32);
            lrow[qt] = lrow[qt] * sc[qt] + ps;
        }
        // O += P @ V
#pragma unroll
        for (int ks2 = 0; ks2 < 2; ++ks2) {
            const int cb = (ks2 * 64 + l4 * 16);
            short8 pf0 = *(const short8*)(Pw + l15 * 128 + (cb ^ ((l15 & 7) << 4)));
            short8 pf1 = *(const short8*)(Pw + (16 + l15) * 128 + (cb ^ ((l15 & 7) << 4)));
#pragma unroll
            for (int dt = 0; dt < 4; ++dt) {
                const int vr = dt * 16 + l15;
                short8 vf = *(const short8*)(Vc + vr * 128 + (cb ^ ((vr & 7) << 4)));
                accO[0][dt] = mfma16(pf0, vf, accO[0][dt]);
                accO[1][dt] = mfma16(pf1, vf, accO[1][dt]);
            }
        }
        // write prefetched tile to the other buffer
        if (pre) {
            unsigned char* Kn = Ks + (c ^ 1) * 8192;
            unsigned char* Vn = Vt + (c ^ 1) * 8192;
#pragma unroll
            for (int it = 0; it < 2; ++it) {
                int row = it * 32 + r0;
                *(short8*)(Kn + row * 128 + ((slot * 16) ^ ((row & 7) << 4))) = kst[it];
            }
#pragma unroll
            for (int u = 0; u < 2; ++u)
#pragma unroll
                for (int j = 0; j < 8; ++j) {
                    int d = wave * 16 + u * 8 + j;
                    *(u16*)(Vn + d * 128 + ((lane * 2) ^ ((d & 7) << 4))) = (u16)vst[u][j];
                }
        }
        __syncthreads();
        c ^= 1;
    };

    for (int kt = 0; kt < 2 * qb; ++kt) step(kt, BC<false>{});
    step(2 * qb, BC<true>{});
    step(last, BC<true>{});

    // epilogue: O = acc / l
#pragma unroll
    for (int rt = 0; rt < 2; ++rt)
#pragma unroll
        for (int r = 0; r < 4; ++r) {
            float lq = __shfl(lrow[rt], l4 * 4 + r);
            float inv = 1.f / lq;
            const int qg = qw0 + rt * 16 + l4 * 4 + r;
#pragma unroll
            for (int dt = 0; dt < 4; ++dt)
                O[bbase + (size_t)qg * E + dt * 16 + l15] = f2bf(accO[rt][dt][r] * inv);
        }
}

extern "C" void kernel_launch(void* const* d_in, const int* in_sizes, int n_in,
                              void* d_out, int out_size, void* d_ws, size_t ws_size,
                              hipStream_t stream)
{
    const float* x    = (const float*)d_in[0];
    const float* ln_w = (const float*)d_in[1];
    const float* ln_b = (const float*)d_in[2];
    const float* Wq   = (const float*)d_in[3];
    const float* Wk   = (const float*)d_in[4];
    const float* Wv   = (const float*)d_in[5];
    const float* Wo   = (const float*)d_in[6];
    const float* bo   = (const float*)d_in[7];
    float* out = (float*)d_out;

    u16* ws  = (u16*)d_ws;
    u16* Wbf = ws;                                  // 4 * 2^20 bf16
    u16* xn  = Wbf + (size_t)4 * 1024 * 1024;       // 4096*1024
    u16* Qb  = xn + (size_t)4096 * 1024;
    u16* Kb  = Qb + (size_t)4096 * 1024;
    u16* Vb  = Kb + (size_t)4096 * 1024;
    u16* Ob  = Vb + (size_t)4096 * 1024;

    convw_k<<<dim3(4096), dim3(256), 0, stream>>>(Wq, Wk, Wv, Wo, Wbf);
    ln_fwd<<<dim3(4096), dim3(256), 0, stream>>>(x, ln_w, ln_b, xn);
    gemm_nt<0><<<dim3(8, 32, 3), dim3(256), 0, stream>>>(
        xn, Wbf, Qb, nullptr, nullptr, nullptr);
    attn_fwd<<<dim3(16, 16, 2), dim3(256), 0, stream>>>(Qb, Kb, Vb, Ob);
    gemm_nt<1><<<dim3(8, 32, 1), dim3(256), 0, stream>>>(
        Ob, Wbf + (size_t)3 * 1024 * 1024, nullptr, out, x, bo);
}

// Round 3
// 165.834 us; speedup vs baseline: 1.3392x; 1.0110x over previous
//
#include <hip/hip_runtime.h>

#define E 1024
#define NSEQ 2048
#define HEADS 16
#define HD 64

typedef unsigned short u16;
typedef short short8 __attribute__((ext_vector_type(8)));
typedef float f32x4 __attribute__((ext_vector_type(4)));
typedef u16 u16x4 __attribute__((ext_vector_type(4)));

template<bool B> struct BC { static constexpr bool v = B; };

__device__ __forceinline__ u16 f2bf(float f) {
    union { float f; unsigned u; } v; v.f = f;
    unsigned r = v.u + 0x7fffu + ((v.u >> 16) & 1u);
    return (u16)(r >> 16);
}

__device__ __forceinline__ f32x4 mfma16(short8 a, short8 b, f32x4 c) {
    return __builtin_amdgcn_mfma_f32_16x16x32_bf16(a, b, c, 0, 0, 0);
}

// ---------------- weight f32 -> bf16 convert ----------------
__global__ __launch_bounds__(256) void convw_k(
    const float* __restrict__ Wq, const float* __restrict__ Wk,
    const float* __restrict__ Wv, const float* __restrict__ Wo,
    u16* __restrict__ out)
{
    const unsigned i = (blockIdx.x * 256u + threadIdx.x) * 4u;
    const unsigned m = i >> 20;
    const float* src = (m == 0) ? Wq : (m == 1) ? Wk : (m == 2) ? Wv : Wo;
    const float4 v = *(const float4*)(src + (i & 0xFFFFFu));
    *(uint2*)(out + i) = make_uint2(
        ((unsigned)f2bf(v.x)) | (((unsigned)f2bf(v.y)) << 16),
        ((unsigned)f2bf(v.z)) | (((unsigned)f2bf(v.w)) << 16));
}

// ---------------- LayerNorm (f32 in, bf16 out) ----------------
__global__ __launch_bounds__(256) void ln_fwd(
    const float* __restrict__ X, const float* __restrict__ w,
    const float* __restrict__ bb, u16* __restrict__ xn)
{
    const int row = blockIdx.x, tid = threadIdx.x;
    const int lane = tid & 63, wave = tid >> 6;
    const float4 v = ((const float4*)(X + (size_t)row * E))[tid];
    float s = v.x + v.y + v.z + v.w;
    float s2 = v.x * v.x + v.y * v.y + v.z * v.z + v.w * v.w;
#pragma unroll
    for (int off = 1; off < 64; off <<= 1) {
        s += __shfl_xor(s, off);
        s2 += __shfl_xor(s2, off);
    }
    __shared__ float red[8];
    if (lane == 0) { red[wave] = s; red[4 + wave] = s2; }
    __syncthreads();
    s = red[0] + red[1] + red[2] + red[3];
    s2 = red[4] + red[5] + red[6] + red[7];
    const float mu = s * (1.f / 1024.f);
    float var = s2 * (1.f / 1024.f) - mu * mu;
    var = fmaxf(var, 0.f);
    const float rs = rsqrtf(var + 1e-5f);
    const float4 wv = ((const float4*)w)[tid];
    const float4 bv = ((const float4*)bb)[tid];
    u16 o0 = f2bf((v.x - mu) * rs * wv.x + bv.x);
    u16 o1 = f2bf((v.y - mu) * rs * wv.y + bv.y);
    u16 o2 = f2bf((v.z - mu) * rs * wv.z + bv.z);
    u16 o3 = f2bf((v.w - mu) * rs * wv.w + bv.w);
    *(uint2*)(xn + (size_t)row * E + tid * 4) =
        make_uint2(((unsigned)o0) | (((unsigned)o1) << 16),
                   ((unsigned)o2) | (((unsigned)o3) << 16));
}

// ---------------- NT GEMM: C[M,1024] = A[M,1024] * B[1024,1024]^T ----------------
// MODE 0: bf16 out at outb + z*4096*1024 (weights at Wbase + z*2^20)
//         z==0 (Q) scaled by 0.125*log2(e) so attention runs in exp2 domain.
// MODE 1: f32 out = acc + resid + bias
template<int MODE>
__global__ __launch_bounds__(256) void gemm_nt(
    const u16* __restrict__ A, const u16* __restrict__ Wbase,
    u16* __restrict__ outb, float* __restrict__ outf,
    const float* __restrict__ resid, const float* __restrict__ bias)
{
    __shared__ __align__(16) unsigned char As[128 * 128];
    __shared__ __align__(16) unsigned char Bs[128 * 128];
    const int tid = threadIdx.x;
    const int lane = tid & 63, wave = tid >> 6;
    const int l15 = lane & 15, l4 = lane >> 4;
    const int wm = wave >> 1, wn = wave & 1;
    const int nt = blockIdx.x, mt = blockIdx.y, z = blockIdx.z;
    const u16* Bw = Wbase + (size_t)z * (E * (size_t)E);

    const int r0 = tid >> 3, slot = tid & 7;

    f32x4 acc[4][4] = {};

    for (int kt = 0; kt < 16; ++kt) {
        short8 va[4], vb[4];
#pragma unroll
        for (int it = 0; it < 4; ++it) {
            int row = it * 32 + r0;
            va[it] = *(const short8*)(A + (size_t)(mt * 128 + row) * E + kt * 64 + slot * 8);
            vb[it] = *(const short8*)(Bw + (size_t)(nt * 128 + row) * E + kt * 64 + slot * 8);
        }
#pragma unroll
        for (int it = 0; it < 4; ++it) {
            int row = it * 32 + r0;
            int off = (row * 128 + slot * 16) ^ ((row & 7) << 4);
            *(short8*)(As + off) = va[it];
            *(short8*)(Bs + off) = vb[it];
        }
        __syncthreads();
#pragma unroll
        for (int ks = 0; ks < 2; ++ks) {
            short8 af[4], bfr[4];
#pragma unroll
            for (int i = 0; i < 4; ++i) {
                int ra = wm * 64 + i * 16 + l15;
                af[i] = *(const short8*)(As + ((ra * 128 + ks * 64 + l4 * 16) ^ ((ra & 7) << 4)));
                int rb = wn * 64 + i * 16 + l15;
                bfr[i] = *(const short8*)(Bs + ((rb * 128 + ks * 64 + l4 * 16) ^ ((rb & 7) << 4)));
            }
#pragma unroll
            for (int i = 0; i < 4; ++i)
#pragma unroll
                for (int j = 0; j < 4; ++j)
                    acc[i][j] = mfma16(af[i], bfr[j], acc[i][j]);
        }
        __syncthreads();
    }

    const int orow0 = mt * 128 + wm * 64, ocol0 = nt * 128 + wn * 64;
    if (MODE == 0) {
        u16* outz = outb + (size_t)z * (4096 * (size_t)E);
        const float osc = (z == 0) ? 0.18033688f : 1.0f;  // 0.125 * log2(e)
#pragma unroll
        for (int i = 0; i < 4; ++i)
#pragma unroll
            for (int j = 0; j < 4; ++j)
#pragma unroll
                for (int r = 0; r < 4; ++r) {
                    int row = orow0 + i * 16 + l4 * 4 + r;
                    int col = ocol0 + j * 16 + l15;
                    outz[(size_t)row * E + col] = f2bf(acc[i][j][r] * osc);
                }
    } else {
#pragma unroll
        for (int i = 0; i < 4; ++i)
#pragma unroll
            for (int j = 0; j < 4; ++j)
#pragma unroll
                for (int r = 0; r < 4; ++r) {
                    int row = orow0 + i * 16 + l4 * 4 + r;
                    int col = ocol0 + j * 16 + l15;
                    size_t idx = (size_t)row * E + col;
                    outf[idx] = acc[i][j][r] + resid[idx] + bias[col];
                }
    }
}

// ---------------- causal flash attention v3 ----------------
// grid (32, 16, 2), block 128 (2 waves x 32 q-rows). QBLK=64, KVBLK=64.
// qb flipped on z so CU-paired blocks have uniform total work.
// K direct global->register (no K LDS); V^T dbuf in LDS; per-wave P strip.
// Softmax in exp2 domain (Q pre-scaled by 0.125*log2e), defer-max THR=8,
// per-lane partial row-sums (no cross-lane ops in steady state).
__global__ __launch_bounds__(128, 2) void attn_fwd(
    const u16* __restrict__ Q, const u16* __restrict__ K,
    const u16* __restrict__ V, u16* __restrict__ O)
{
    __shared__ __align__(16) unsigned char Vt[2 * 64 * 128];  // V^T dbuf [d][kv]
    __shared__ __align__(16) unsigned char Ps[2 * 32 * 128];  // per-wave P [32 q][64 kv]
    const int tid = threadIdx.x, lane = tid & 63, wave = tid >> 6;
    const int l15 = lane & 15, l4 = lane >> 4;
    const int h = blockIdx.y, b = blockIdx.z;
    const int qb = (b == 0) ? (int)blockIdx.x : 31 - (int)blockIdx.x;
    const int qw0 = qb * 64 + wave * 32;
    const size_t bbase = (size_t)b * NSEQ * E + h * HD;
    const int ntiles = qb + 1;

    // Q frags (B-operand): lane holds Q[qw0+qt*16+l15][ks*32+l4*8 ..+8]
    short8 aq[2][2];
#pragma unroll
    for (int qt = 0; qt < 2; ++qt)
#pragma unroll
        for (int ks = 0; ks < 2; ++ks)
            aq[qt][ks] = *(const short8*)(Q + bbase + (size_t)(qw0 + qt * 16 + l15) * E + ks * 32 + l4 * 8);

    f32x4 accO[2][4] = {};
    float mrow[2] = {-1e30f, -1e30f};
    float lrow[2] = {0.f, 0.f};  // per-lane PARTIAL row sums (reduced in epilogue)

    unsigned char* Pw = Ps + wave * 4096;

    // K frags (A-operand) + V rows, single-buffered registers, 1-tile prefetch
    short8 kf[4][2], vst[4];
    {
        const u16* Kg = K + bbase;
        const u16* Vg = V + bbase;
#pragma unroll
        for (int u = 0; u < 4; ++u)
            vst[u] = *(const short8*)(Vg + (size_t)lane * E + wave * 32 + u * 8);
#pragma unroll
        for (int kvt = 0; kvt < 4; ++kvt)
#pragma unroll
            for (int ks = 0; ks < 2; ++ks)
                kf[kvt][ks] = *(const short8*)(Kg + (size_t)(kvt * 16 + l15) * E + ks * 32 + l4 * 8);
        // write V^T tile 0 -> buf 0
#pragma unroll
        for (int u = 0; u < 4; ++u)
#pragma unroll
            for (int j = 0; j < 8; ++j) {
                int d = wave * 32 + u * 8 + j;
                *(u16*)(Vt + d * 128 + ((lane * 2) ^ ((d & 7) << 4))) = (u16)vst[u][j];
            }
    }
    __syncthreads();

    auto step = [&](int kt, auto mc) {
        constexpr bool MASK = decltype(mc)::v;
        const unsigned char* Vc = Vt + (kt & 1) * 8192;
        const bool pre = (kt + 1) < ntiles;

        // S^T = K . Q^T : lane owns q=qw0+qt*16+l15, kv=kt*64+kvt*16+l4*4+r
        f32x4 s[2][4] = {};
#pragma unroll
        for (int kvt = 0; kvt < 4; ++kvt)
#pragma unroll
            for (int ks = 0; ks < 2; ++ks) {
                s[0][kvt] = mfma16(kf[kvt][ks], aq[0][ks], s[0][kvt]);
                s[1][kvt] = mfma16(kf[kvt][ks], aq[1][ks], s[1][kvt]);
            }

        // issue next-tile loads (kf/vst regs are dead after the mfmas above)
        if (pre) {
            const u16* Kg = K + bbase + (size_t)((kt + 1) * 64) * E;
            const u16* Vg = V + bbase + (size_t)((kt + 1) * 64) * E;
#pragma unroll
            for (int u = 0; u < 4; ++u)
                vst[u] = *(const short8*)(Vg + (size_t)lane * E + wave * 32 + u * 8);
#pragma unroll
            for (int kvt = 0; kvt < 4; ++kvt)
#pragma unroll
                for (int ks = 0; ks < 2; ++ks)
                    kf[kvt][ks] = *(const short8*)(Kg + (size_t)(kvt * 16 + l15) * E + ks * 32 + l4 * 8);
        }

        if constexpr (MASK) {
#pragma unroll
            for (int qt = 0; qt < 2; ++qt) {
                const int qg = qw0 + qt * 16 + l15;
#pragma unroll
                for (int kvt = 0; kvt < 4; ++kvt)
#pragma unroll
                    for (int r = 0; r < 4; ++r) {
                        int kvg = kt * 64 + kvt * 16 + l4 * 4 + r;
                        if (kvg > qg) s[qt][kvt][r] = -1e30f;
                    }
            }
        }

        // softmax (exp2 domain), defer-max, no cross-lane in steady state
#pragma unroll
        for (int qt = 0; qt < 2; ++qt) {
            float m0 = fmaxf(fmaxf(s[qt][0][0], s[qt][0][1]), fmaxf(s[qt][0][2], s[qt][0][3]));
            float m1 = fmaxf(fmaxf(s[qt][1][0], s[qt][1][1]), fmaxf(s[qt][1][2], s[qt][1][3]));
            float m2 = fmaxf(fmaxf(s[qt][2][0], s[qt][2][1]), fmaxf(s[qt][2][2], s[qt][2][3]));
            float m3 = fmaxf(fmaxf(s[qt][3][0], s[qt][3][1]), fmaxf(s[qt][3][2], s[qt][3][3]));
            float pm = fmaxf(fmaxf(m0, m1), fmaxf(m2, m3));  // in-lane max (own kv subset)
            if (__any(pm > mrow[qt] + 8.f)) {
                pm = fmaxf(pm, __shfl_xor(pm, 16));
                pm = fmaxf(pm, __shfl_xor(pm, 32));
                const float mn = fmaxf(mrow[qt], pm);
                const float sc = exp2f(mrow[qt] - mn);
                mrow[qt] = mn;
                lrow[qt] *= sc;
#pragma unroll
                for (int r = 0; r < 4; ++r) {
                    float scv = __shfl(sc, l4 * 4 + r);
#pragma unroll
                    for (int dt = 0; dt < 4; ++dt) accO[qt][dt][r] *= scv;
                }
            }
            const int pr = qt * 16 + l15;
            const int sw = (l15 & 7) << 4;
#pragma unroll
            for (int kvt = 0; kvt < 4; ++kvt) {
                u16x4 pk;
#pragma unroll
                for (int r = 0; r < 4; ++r) {
                    float p = exp2f(s[qt][kvt][r] - mrow[qt]);
                    lrow[qt] += p;
                    pk[r] = f2bf(p);
                }
                *(u16x4*)(Pw + pr * 128 + ((kvt * 32 + l4 * 8) ^ sw)) = pk;
            }
        }

        // O += P @ V
#pragma unroll
        for (int ks2 = 0; ks2 < 2; ++ks2) {
            const int cb = ks2 * 64 + l4 * 16;
            short8 pf0 = *(const short8*)(Pw + l15 * 128 + (cb ^ ((l15 & 7) << 4)));
            short8 pf1 = *(const short8*)(Pw + (16 + l15) * 128 + (cb ^ ((l15 & 7) << 4)));
#pragma unroll
            for (int dt = 0; dt < 4; ++dt) {
                const int vr = dt * 16 + l15;
                short8 vf = *(const short8*)(Vc + vr * 128 + (cb ^ ((vr & 7) << 4)));
                accO[0][dt] = mfma16(pf0, vf, accO[0][dt]);
                accO[1][dt] = mfma16(pf1, vf, accO[1][dt]);
            }
        }

        // stage V^T(kt+1) into the other buffer
        if (pre) {
            unsigned char* Vn = Vt + ((kt + 1) & 1) * 8192;
#pragma unroll
            for (int u = 0; u < 4; ++u)
#pragma unroll
                for (int j = 0; j < 8; ++j) {
                    int d = wave * 32 + u * 8 + j;
                    *(u16*)(Vn + d * 128 + ((lane * 2) ^ ((d & 7) << 4))) = (u16)vst[u][j];
                }
        }
        __syncthreads();
    };

    for (int kt = 0; kt + 1 < ntiles; ++kt) step(kt, BC<false>{});
    step(ntiles - 1, BC<true>{});

    // epilogue: reduce partial l, O = acc / l
    float linv[2];
#pragma unroll
    for (int qt = 0; qt < 2; ++qt) {
        float t = lrow[qt];
        t += __shfl_xor(t, 16);
        t += __shfl_xor(t, 32);
        linv[qt] = 1.f / t;
    }
#pragma unroll
    for (int rt = 0; rt < 2; ++rt)
#pragma unroll
        for (int r = 0; r < 4; ++r) {
            float lq = __shfl(linv[rt], l4 * 4 + r);
            const int qg = qw0 + rt * 16 + l4 * 4 + r;
#pragma unroll
            for (int dt = 0; dt < 4; ++dt)
                O[bbase + (size_t)qg * E + dt * 16 + l15] = f2bf(accO[rt][dt][r] * lq);
        }
}

extern "C" void kernel_launch(void* const* d_in, const int* in_sizes, int n_in,
                              void* d_out, int out_size, void* d_ws, size_t ws_size,
                              hipStream_t stream)
{
    const float* x    = (const float*)d_in[0];
    const float* ln_w = (const float*)d_in[1];
    const float* ln_b = (const float*)d_in[2];
    const float* Wq   = (const float*)d_in[3];
    const float* Wk   = (const float*)d_in[4];
    const float* Wv   = (const float*)d_in[5];
    const float* Wo   = (const float*)d_in[6];
    const float* bo   = (const float*)d_in[7];
    float* out = (float*)d_out;

    u16* ws  = (u16*)d_ws;
    u16* Wbf = ws;                                  // 4 * 2^20 bf16
    u16* xn  = Wbf + (size_t)4 * 1024 * 1024;       // 4096*1024
    u16* Qb  = xn + (size_t)4096 * 1024;
    u16* Kb  = Qb + (size_t)4096 * 1024;
    u16* Vb  = Kb + (size_t)4096 * 1024;
    u16* Ob  = Vb + (size_t)4096 * 1024;

    convw_k<<<dim3(4096), dim3(256), 0, stream>>>(Wq, Wk, Wv, Wo, Wbf);
    ln_fwd<<<dim3(4096), dim3(256), 0, stream>>>(x, ln_w, ln_b, xn);
    gemm_nt<0><<<dim3(8, 32, 3), dim3(256), 0, stream>>>(
        xn, Wbf, Qb, nullptr, nullptr, nullptr);
    attn_fwd<<<dim3(32, 16, 2), dim3(128), 0, stream>>>(Qb, Kb, Vb, Ob);
    gemm_nt<1><<<dim3(8, 32, 1), dim3(256), 0, stream>>>(
        Ob, Wbf + (size_t)3 * 1024 * 1024, nullptr, out, x, bo);
}

// Round 4
// 146.786 us; speedup vs baseline: 1.5130x; 1.1298x over previous
//
#include <hip/hip_runtime.h>

#define E 1024
#define NSEQ 2048
#define HEADS 16
#define HD 64

typedef unsigned short u16;
typedef short short8 __attribute__((ext_vector_type(8)));
typedef float f32x4 __attribute__((ext_vector_type(4)));

template<bool B> struct BC { static constexpr bool v = B; };

#define GLOAD_LDS16(gp, lp)                                        \
    __builtin_amdgcn_global_load_lds(                              \
        (const __attribute__((address_space(1))) void*)(gp),       \
        (__attribute__((address_space(3))) void*)(lp), 16, 0, 0)

__device__ __forceinline__ u16 f2bf(float f) {
    union { float f; unsigned u; } v; v.f = f;
    unsigned r = v.u + 0x7fffu + ((v.u >> 16) & 1u);
    return (u16)(r >> 16);
}

__device__ __forceinline__ unsigned cvt_pk_bf16(float lo, float hi) {
    unsigned r;
    asm("v_cvt_pk_bf16_f32 %0, %1, %2" : "=v"(r) : "v"(lo), "v"(hi));
    return r;
}

__device__ __forceinline__ f32x4 mfma16(short8 a, short8 b, f32x4 c) {
    return __builtin_amdgcn_mfma_f32_16x16x32_bf16(a, b, c, 0, 0, 0);
}

// ---------------- weight f32 -> bf16 convert ----------------
__global__ __launch_bounds__(256) void convw_k(
    const float* __restrict__ Wq, const float* __restrict__ Wk,
    const float* __restrict__ Wv, const float* __restrict__ Wo,
    u16* __restrict__ out)
{
    const unsigned i = (blockIdx.x * 256u + threadIdx.x) * 4u;
    const unsigned m = i >> 20;
    const float* src = (m == 0) ? Wq : (m == 1) ? Wk : (m == 2) ? Wv : Wo;
    const float4 v = *(const float4*)(src + (i & 0xFFFFFu));
    *(uint2*)(out + i) = make_uint2(
        ((unsigned)f2bf(v.x)) | (((unsigned)f2bf(v.y)) << 16),
        ((unsigned)f2bf(v.z)) | (((unsigned)f2bf(v.w)) << 16));
}

// ---------------- LayerNorm (f32 in, bf16 out) ----------------
__global__ __launch_bounds__(256) void ln_fwd(
    const float* __restrict__ X, const float* __restrict__ w,
    const float* __restrict__ bb, u16* __restrict__ xn)
{
    const int row = blockIdx.x, tid = threadIdx.x;
    const int lane = tid & 63, wave = tid >> 6;
    const float4 v = ((const float4*)(X + (size_t)row * E))[tid];
    float s = v.x + v.y + v.z + v.w;
    float s2 = v.x * v.x + v.y * v.y + v.z * v.z + v.w * v.w;
#pragma unroll
    for (int off = 1; off < 64; off <<= 1) {
        s += __shfl_xor(s, off);
        s2 += __shfl_xor(s2, off);
    }
    __shared__ float red[8];
    if (lane == 0) { red[wave] = s; red[4 + wave] = s2; }
    __syncthreads();
    s = red[0] + red[1] + red[2] + red[3];
    s2 = red[4] + red[5] + red[6] + red[7];
    const float mu = s * (1.f / 1024.f);
    float var = s2 * (1.f / 1024.f) - mu * mu;
    var = fmaxf(var, 0.f);
    const float rs = rsqrtf(var + 1e-5f);
    const float4 wv = ((const float4*)w)[tid];
    const float4 bv = ((const float4*)bb)[tid];
    u16 o0 = f2bf((v.x - mu) * rs * wv.x + bv.x);
    u16 o1 = f2bf((v.y - mu) * rs * wv.y + bv.y);
    u16 o2 = f2bf((v.z - mu) * rs * wv.z + bv.z);
    u16 o3 = f2bf((v.w - mu) * rs * wv.w + bv.w);
    *(uint2*)(xn + (size_t)row * E + tid * 4) =
        make_uint2(((unsigned)o0) | (((unsigned)o1) << 16),
                   ((unsigned)o2) | (((unsigned)o3) << 16));
}

// ---------------- V transpose: V[b][n][h*64+d] -> VT[(b*16+h)][d][n] ----------------
__global__ __launch_bounds__(256) void vtrans(
    const u16* __restrict__ Vb, u16* __restrict__ VT)
{
    __shared__ u16 tl[64][65];
    const int t = threadIdx.x;
    const int ntile = blockIdx.x, bh = blockIdx.y;
    const int b = bh >> 4, h = bh & 15;
    const int n0 = ntile * 64;
    // load 64 n-rows x 64 d (coalesced b128)
    {
        const int nl = t >> 2;
        const u16* src = Vb + ((size_t)b * NSEQ + n0 + nl) * E + h * 64;
#pragma unroll
        for (int u = 0; u < 2; ++u) {
            const int d0 = (t & 3) * 16 + u * 8;
            short8 v = *(const short8*)(src + d0);
#pragma unroll
            for (int j = 0; j < 8; ++j) tl[nl][d0 + j] = (u16)v[j];
        }
    }
    __syncthreads();
    // write 64 d-rows x 64 n (coalesced)
    {
        const int d = t >> 2, nc = (t & 3) * 16;
        u16* dst = VT + ((size_t)bh * 64 + d) * NSEQ + n0 + nc;
#pragma unroll
        for (int u = 0; u < 2; ++u) {
            short8 o;
#pragma unroll
            for (int j = 0; j < 8; ++j) o[j] = (short)tl[nc + u * 8 + j][d];
            *(short8*)(dst + u * 8) = o;
        }
    }
}

// ---------------- NT GEMM: C[M,1024] = A[M,1024] * B[1024,1024]^T ----------------
// m97 structure: global_load_lds w16, pre-swizzled source, swizzled ds_read_b128.
// MODE 0: bf16 out at outb + z*4096*1024 (weights at Wbase + z*2^20)
//         z==0 (Q) scaled by 0.125*log2(e) so attention runs in exp2 domain.
// MODE 1: f32 out = acc + resid + bias
template<int MODE>
__global__ __launch_bounds__(256) void gemm_nt(
    const u16* __restrict__ A, const u16* __restrict__ Wbase,
    u16* __restrict__ outb, float* __restrict__ outf,
    const float* __restrict__ resid, const float* __restrict__ bias)
{
    __shared__ __align__(16) unsigned char As[128 * 128];  // 128 rows x 64 bf16 (128B)
    __shared__ __align__(16) unsigned char Bs[128 * 128];
    const int tid = threadIdx.x;
    const int lane = tid & 63, wave = tid >> 6;
    const int l15 = lane & 15, l4 = lane >> 4;
    const int wm = wave >> 1, wn = wave & 1;
    const int nt = blockIdx.x, mt = blockIdx.y, z = blockIdx.z;
    const u16* Bw = Wbase + (size_t)z * (E * (size_t)E);

    // staging source: lane l covers row (l>>3), swizzled 16B chunk (l&7)^(l>>3)
    const int lrow8 = lane >> 3;
    const int lchunk = (lane & 7) ^ lrow8;
    const u16* gA = A + (size_t)(mt * 128 + lrow8) * E + lchunk * 8;
    const u16* gB = Bw + (size_t)(nt * 128 + lrow8) * E + lchunk * 8;

    f32x4 acc[4][4] = {};

    for (int kt = 0; kt < 16; ++kt) {
#pragma unroll
        for (int i = 0; i < 4; ++i) {
            const int rb = (i * 4 + wave) * 8;   // wave-uniform row base
            GLOAD_LDS16(gA + (size_t)rb * E + kt * 64, As + rb * 128);
            GLOAD_LDS16(gB + (size_t)rb * E + kt * 64, Bs + rb * 128);
        }
        __syncthreads();
#pragma unroll
        for (int ks = 0; ks < 2; ++ks) {
            short8 af[4], bfr[4];
#pragma unroll
            for (int i = 0; i < 4; ++i) {
                int ra = wm * 64 + i * 16 + l15;
                af[i] = *(const short8*)(As + ra * 128 + ((ks * 64 + l4 * 16) ^ ((ra & 7) << 4)));
                int rb2 = wn * 64 + i * 16 + l15;
                bfr[i] = *(const short8*)(Bs + rb2 * 128 + ((ks * 64 + l4 * 16) ^ ((rb2 & 7) << 4)));
            }
#pragma unroll
            for (int i = 0; i < 4; ++i)
#pragma unroll
                for (int j = 0; j < 4; ++j)
                    acc[i][j] = mfma16(af[i], bfr[j], acc[i][j]);
        }
        __syncthreads();
    }

    const int orow0 = mt * 128 + wm * 64, ocol0 = nt * 128 + wn * 64;
    if (MODE == 0) {
        u16* outz = outb + (size_t)z * (4096 * (size_t)E);
        const float osc = (z == 0) ? 0.18033688f : 1.0f;  // 0.125 * log2(e)
#pragma unroll
        for (int i = 0; i < 4; ++i)
#pragma unroll
            for (int j = 0; j < 4; ++j)
#pragma unroll
                for (int r = 0; r < 4; ++r) {
                    int row = orow0 + i * 16 + l4 * 4 + r;
                    int col = ocol0 + j * 16 + l15;
                    outz[(size_t)row * E + col] = f2bf(acc[i][j][r] * osc);
                }
    } else {
#pragma unroll
        for (int i = 0; i < 4; ++i)
#pragma unroll
            for (int j = 0; j < 4; ++j)
#pragma unroll
                for (int r = 0; r < 4; ++r) {
                    int row = orow0 + i * 16 + l4 * 4 + r;
                    int col = ocol0 + j * 16 + l15;
                    size_t idx = (size_t)row * E + col;
                    outf[idx] = acc[i][j][r] + resid[idx] + bias[col];
                }
    }
}

// ---------------- causal flash attention v4 ----------------
// grid (32, 16, 2), block 128 (2 waves x 32 q-rows). KVBLK=64.
// NO barriers in the K-loop: K and V^T frags load global->register
// (V pre-transposed by vtrans); only per-wave P strip uses LDS.
// exp2 domain (Q pre-scaled), defer-max THR=8, per-lane partial sums.
__global__ __launch_bounds__(128, 2) void attn_fwd(
    const u16* __restrict__ Q, const u16* __restrict__ K,
    const u16* __restrict__ VT, u16* __restrict__ O)
{
    __shared__ __align__(16) unsigned char Ps[2 * 32 * 128];  // per-wave P [32 q][64 kv]
    const int tid = threadIdx.x, lane = tid & 63, wave = tid >> 6;
    const int l15 = lane & 15, l4 = lane >> 4;
    const int h = blockIdx.y, b = blockIdx.z;
    const int qb = (b == 0) ? (int)blockIdx.x : 31 - (int)blockIdx.x;
    const int qw0 = qb * 64 + wave * 32;
    const size_t bbase = (size_t)b * NSEQ * E + h * HD;
    const u16* vt = VT + ((size_t)(b * 16 + h) * 64) * NSEQ;  // [d][n]
    const int ntiles = qb + 1;

    // Q frags: lane holds Q[qw0+qt*16+l15][ks*32+l4*8 ..+8]
    short8 aq[2][2];
#pragma unroll
    for (int qt = 0; qt < 2; ++qt)
#pragma unroll
        for (int ks = 0; ks < 2; ++ks)
            aq[qt][ks] = *(const short8*)(Q + bbase + (size_t)(qw0 + qt * 16 + l15) * E + ks * 32 + l4 * 8);

    f32x4 accO[2][4] = {};
    float mrow[2] = {-1e30f, -1e30f};
    float lrow[2] = {0.f, 0.f};

    unsigned char* Pw = Ps + wave * 4096;

    // K frags (A-operand) + V^T frags (B-operand), tile 0
    short8 kf[4][2], vf[2][4];
    {
        const u16* Kg = K + bbase;
#pragma unroll
        for (int kvt = 0; kvt < 4; ++kvt)
#pragma unroll
            for (int ks = 0; ks < 2; ++ks)
                kf[kvt][ks] = *(const short8*)(Kg + (size_t)(kvt * 16 + l15) * E + ks * 32 + l4 * 8);
#pragma unroll
        for (int ks2 = 0; ks2 < 2; ++ks2)
#pragma unroll
            for (int dt = 0; dt < 4; ++dt)
                vf[ks2][dt] = *(const short8*)(vt + (size_t)(dt * 16 + l15) * NSEQ + ks2 * 32 + l4 * 8);
    }

    auto step = [&](int kt, auto mc) {
        constexpr bool MASK = decltype(mc)::v;
        const bool pre = (kt + 1) < ntiles;

        // S^T = K . Q^T : lane owns q=qw0+qt*16+l15, kv=kt*64+kvt*16+l4*4+r
        f32x4 s[2][4] = {};
#pragma unroll
        for (int kvt = 0; kvt < 4; ++kvt)
#pragma unroll
            for (int ks = 0; ks < 2; ++ks) {
                s[0][kvt] = mfma16(kf[kvt][ks], aq[0][ks], s[0][kvt]);
                s[1][kvt] = mfma16(kf[kvt][ks], aq[1][ks], s[1][kvt]);
            }

        // prefetch next K tile (kf regs consumed above)
        if (pre) {
            const u16* Kg = K + bbase + (size_t)((kt + 1) * 64) * E;
#pragma unroll
            for (int kvt = 0; kvt < 4; ++kvt)
#pragma unroll
                for (int ks = 0; ks < 2; ++ks)
                    kf[kvt][ks] = *(const short8*)(Kg + (size_t)(kvt * 16 + l15) * E + ks * 32 + l4 * 8);
        }

        if constexpr (MASK) {
#pragma unroll
            for (int qt = 0; qt < 2; ++qt) {
                const int qg = qw0 + qt * 16 + l15;
#pragma unroll
                for (int kvt = 0; kvt < 4; ++kvt)
#pragma unroll
                    for (int r = 0; r < 4; ++r) {
                        int kvg = kt * 64 + kvt * 16 + l4 * 4 + r;
                        if (kvg > qg) s[qt][kvt][r] = -1e30f;
                    }
            }
        }

        // softmax (exp2 domain), defer-max, per-lane partial sums
#pragma unroll
        for (int qt = 0; qt < 2; ++qt) {
            float m0 = fmaxf(fmaxf(s[qt][0][0], s[qt][0][1]), fmaxf(s[qt][0][2], s[qt][0][3]));
            float m1 = fmaxf(fmaxf(s[qt][1][0], s[qt][1][1]), fmaxf(s[qt][1][2], s[qt][1][3]));
            float m2 = fmaxf(fmaxf(s[qt][2][0], s[qt][2][1]), fmaxf(s[qt][2][2], s[qt][2][3]));
            float m3 = fmaxf(fmaxf(s[qt][3][0], s[qt][3][1]), fmaxf(s[qt][3][2], s[qt][3][3]));
            float pm = fmaxf(fmaxf(m0, m1), fmaxf(m2, m3));
            if (__any(pm > mrow[qt] + 8.f)) {
                pm = fmaxf(pm, __shfl_xor(pm, 16));
                pm = fmaxf(pm, __shfl_xor(pm, 32));
                const float mn = fmaxf(mrow[qt], pm);
                const float sc = exp2f(mrow[qt] - mn);
                mrow[qt] = mn;
                lrow[qt] *= sc;
#pragma unroll
                for (int r = 0; r < 4; ++r) {
                    float scv = __shfl(sc, l4 * 4 + r);
#pragma unroll
                    for (int dt = 0; dt < 4; ++dt) accO[qt][dt][r] *= scv;
                }
            }
            const int pr = qt * 16 + l15;
            const int sw = (l15 & 7) << 4;
#pragma unroll
            for (int kvt = 0; kvt < 4; ++kvt) {
                float p0 = exp2f(s[qt][kvt][0] - mrow[qt]);
                float p1 = exp2f(s[qt][kvt][1] - mrow[qt]);
                float p2 = exp2f(s[qt][kvt][2] - mrow[qt]);
                float p3 = exp2f(s[qt][kvt][3] - mrow[qt]);
                lrow[qt] += (p0 + p1) + (p2 + p3);
                uint2 pk = make_uint2(cvt_pk_bf16(p0, p1), cvt_pk_bf16(p2, p3));
                *(uint2*)(Pw + pr * 128 + ((kvt * 32 + l4 * 8) ^ sw)) = pk;
            }
        }

        // O += P @ V (pf from own-wave LDS strip; vf in regs)
#pragma unroll
        for (int ks2 = 0; ks2 < 2; ++ks2) {
            const int cb = ks2 * 64 + l4 * 16;
            short8 pf0 = *(const short8*)(Pw + l15 * 128 + (cb ^ ((l15 & 7) << 4)));
            short8 pf1 = *(const short8*)(Pw + (16 + l15) * 128 + (cb ^ ((l15 & 7) << 4)));
#pragma unroll
            for (int dt = 0; dt < 4; ++dt) {
                accO[0][dt] = mfma16(pf0, vf[ks2][dt], accO[0][dt]);
                accO[1][dt] = mfma16(pf1, vf[ks2][dt], accO[1][dt]);
            }
        }

        // prefetch next V^T tile (vf regs consumed above)
        if (pre) {
            const u16* vg = vt + (kt + 1) * 64;
#pragma unroll
            for (int ks2 = 0; ks2 < 2; ++ks2)
#pragma unroll
                for (int dt = 0; dt < 4; ++dt)
                    vf[ks2][dt] = *(const short8*)(vg + (size_t)(dt * 16 + l15) * NSEQ + ks2 * 32 + l4 * 8);
        }
    };

    for (int kt = 0; kt + 1 < ntiles; ++kt) step(kt, BC<false>{});
    step(ntiles - 1, BC<true>{});

    // epilogue: reduce partial l, O = acc / l
    float linv[2];
#pragma unroll
    for (int qt = 0; qt < 2; ++qt) {
        float t = lrow[qt];
        t += __shfl_xor(t, 16);
        t += __shfl_xor(t, 32);
        linv[qt] = 1.f / t;
    }
#pragma unroll
    for (int rt = 0; rt < 2; ++rt)
#pragma unroll
        for (int r = 0; r < 4; ++r) {
            float lq = __shfl(linv[rt], l4 * 4 + r);
            const int qg = qw0 + rt * 16 + l4 * 4 + r;
#pragma unroll
            for (int dt = 0; dt < 4; ++dt)
                O[bbase + (size_t)qg * E + dt * 16 + l15] = f2bf(accO[rt][dt][r] * lq);
        }
}

extern "C" void kernel_launch(void* const* d_in, const int* in_sizes, int n_in,
                              void* d_out, int out_size, void* d_ws, size_t ws_size,
                              hipStream_t stream)
{
    const float* x    = (const float*)d_in[0];
    const float* ln_w = (const float*)d_in[1];
    const float* ln_b = (const float*)d_in[2];
    const float* Wq   = (const float*)d_in[3];
    const float* Wk   = (const float*)d_in[4];
    const float* Wv   = (const float*)d_in[5];
    const float* Wo   = (const float*)d_in[6];
    const float* bo   = (const float*)d_in[7];
    float* out = (float*)d_out;

    u16* ws  = (u16*)d_ws;
    u16* Wbf = ws;                                  // 4 * 2^20 bf16
    u16* xn  = Wbf + (size_t)4 * 1024 * 1024;       // 4096*1024 (reused as VT after gemm0)
    u16* Qb  = xn + (size_t)4096 * 1024;
    u16* Kb  = Qb + (size_t)4096 * 1024;
    u16* Vb  = Kb + (size_t)4096 * 1024;
    u16* Ob  = Vb + (size_t)4096 * 1024;
    u16* VT  = xn;  // alias: xn dead after gemm<0>; VT = [32 bh][64 d][2048 n]

    convw_k<<<dim3(4096), dim3(256), 0, stream>>>(Wq, Wk, Wv, Wo, Wbf);
    ln_fwd<<<dim3(4096), dim3(256), 0, stream>>>(x, ln_w, ln_b, xn);
    gemm_nt<0><<<dim3(8, 32, 3), dim3(256), 0, stream>>>(
        xn, Wbf, Qb, nullptr, nullptr, nullptr);
    vtrans<<<dim3(32, 32), dim3(256), 0, stream>>>(Vb, VT);
    attn_fwd<<<dim3(32, 16, 2), dim3(128), 0, stream>>>(Qb, Kb, VT, Ob);
    gemm_nt<1><<<dim3(8, 32, 1), dim3(256), 0, stream>>>(
        Ob, Wbf + (size_t)3 * 1024 * 1024, nullptr, out, x, bo);
}